// Round 18
// baseline (593.350 us; speedup 1.0000x reference)
//
#include <hip/hip_runtime.h>

#define NGRAPH 100
#define NPER   1000
#define NNODES 100000
#define NEDGES 1600000
#define EPG    16000   // edges per graph

typedef float v2f __attribute__((ext_vector_type(2)));

// DPP-based add of a permuted lane; VALU latency.
template <int CTRL>
__device__ __forceinline__ float dpp_add(float x) {
    int yi = __builtin_amdgcn_update_dpp(0, __float_as_int(x), CTRL, 0xF, 0xF, true);
    return x + __int_as_float(yi);
}
#define DPP_XOR1 0xB1   // quad_perm [1,0,3,2]
#define DPP_XOR2 0x4E   // quad_perm [2,3,0,1]  (XOR1+XOR2 = 4-lane sum)

// bf16x2 (packed in u32) -> 2 floats
__device__ __forceinline__ v2f bf2f(unsigned u) {
    v2f r;
    r.x = __uint_as_float(u << 16);
    r.y = __uint_as_float(u & 0xffff0000u);
    return r;
}
// 2 floats -> bf16x2 (round-to-nearest-ish)
__device__ __forceinline__ unsigned pkbf(float a, float b) {
    unsigned ua = (__float_as_uint(a) + 0x8000u) >> 16;
    unsigned ub = (__float_as_uint(b) + 0x8000u) & 0xffff0000u;
    return ua | ub;
}

// ==================== utility: zero count + g_acc in one launch ============
__global__ __launch_bounds__(256) void zero2_k(int* __restrict__ count,
                                               float* __restrict__ g_acc) {
    int i = blockIdx.x * 256 + threadIdx.x;
    if (i < NNODES) count[i] = 0;
    if (i < NGRAPH * 96) g_acc[i] = 0.f;
}

// ==================== counting sort of edges by DST ====================
__global__ __launch_bounds__(256) void hist_k(const int* __restrict__ dst,
                                              int* __restrict__ count) {
    int e = blockIdx.x * 256 + threadIdx.x;
    if (e < NEDGES) atomicAdd(&count[dst[e]], 1);
}

__global__ __launch_bounds__(1024) void scan_k(const int* __restrict__ count,
                                               int* __restrict__ offs,
                                               int* __restrict__ cursor) {
    __shared__ int sc[1024];
    int t = threadIdx.x, g = blockIdx.x;
    int v = (t < NPER) ? count[g * NPER + t] : 0;
    sc[t] = v;
    __syncthreads();
    for (int s = 1; s < 1024; s <<= 1) {
        int add = (t >= s) ? sc[t - s] : 0;
        __syncthreads();
        sc[t] += add;
        __syncthreads();
    }
    if (t < NPER) {
        int start = g * EPG + sc[t] - v;   // exclusive
        offs[g * NPER + t]   = start;
        cursor[g * NPER + t] = start;
    }
}

// compressed record: {src*16, etype | elabel<<16}
__global__ __launch_bounds__(256) void scatter_k(
    const int* __restrict__ src, const int* __restrict__ dst,
    const int* __restrict__ et, const int* __restrict__ el,
    int* __restrict__ cursor, int2* __restrict__ sorted2) {
    int e = blockIdx.x * 256 + threadIdx.x;
    if (e >= NEDGES) return;
    int d = dst[e];
    int p = atomicAdd(&cursor[d], 1);
    sorted2[p] = make_int2(src[e] * 16, et[e] | (el[e] << 16));
}

// ==================== node projections (R14-verified structure) ============
// grid (391, 7).
// y=0..3: xproj (bf16, pair-packed) channels [y*8,y*8+8) -> one 64B line.
// y=4,5:  psrc/pdst/selfp f32 channel halves -> full 64B line per matrix.
// y=6:    rel tables t1b/t2b (bf16 pairs).
__device__ __forceinline__ float4 dot32x4(const float* __restrict__ w,
                                          const float* hreg, int oc) {
    float4 a = {0.f, 0.f, 0.f, 0.f};
    #pragma unroll 4
    for (int d = 0; d < 32; d++) {
        float4 wv = *(const float4*)(w + d * 32 + oc * 4);
        a.x = fmaf(hreg[d], wv.x, a.x);
        a.y = fmaf(hreg[d], wv.y, a.y);
        a.z = fmaf(hreg[d], wv.z, a.z);
        a.w = fmaf(hreg[d], wv.w, a.w);
    }
    return a;
}

__global__ __launch_bounds__(256, 4) void node_k(
    const float* __restrict__ h, const float* __restrict__ basis_l,
    const float* __restrict__ selfw_l, const float* __restrict__ Aw_l,
    const float* __restrict__ Ab_l, const float* __restrict__ attn_tab,
    uint4* __restrict__ xproj_b, float* __restrict__ psrc,
    float* __restrict__ pdst, float* __restrict__ selfp,
    unsigned* __restrict__ t1b, unsigned* __restrict__ t2b)
{
    const int y = blockIdx.y;
    if (y == 6) {   // rel tables: r = bid*4 + wave, 64 threads per r
        int r = blockIdx.x * 4 + (threadIdx.x >> 6);
        if (r >= 200) return;
        int t = threadIdx.x & 63;
        int o = t & 31;
        bool second = t >= 32;
        const float* at = attn_tab + r * 32;
        const float* W  = Aw_l + (second ? 96*32 : 64*32);
        float acc = second ? 0.f : Ab_l[o];
        #pragma unroll 8
        for (int d = 0; d < 32; d++) acc += at[d] * W[d*32 + o];
        float nb = __shfl_down(acc, 1);
        unsigned u = pkbf(acc, nb);
        if (!(o & 1)) (second ? t2b : t1b)[r*16 + (o >> 1)] = u;
        return;
    }

    __shared__ float w_s[4096];
    if (y < 4) {
        const float4* b4 = (const float4*)basis_l;   // 1024 float4
        float4* w4 = (float4*)w_s;
        for (int k = threadIdx.x; k < 1024; k += 256) w4[k] = b4[k];
    } else {
        const float4* a4 = (const float4*)Aw_l;      // 512 float4 (rows 0..63)
        const float4* s4 = (const float4*)selfw_l;   // 256 float4
        float4* w4 = (float4*)w_s;
        for (int k = threadIdx.x; k < 768; k += 256)
            w4[k] = (k < 512) ? a4[k] : s4[k - 512];
    }
    __syncthreads();

    int n = blockIdx.x * 256 + threadIdx.x;
    if (n >= NNODES) return;

    float hreg[32];
    {
        const float4* hp = (const float4*)(h + n * 32);
        #pragma unroll
        for (int k = 0; k < 8; k++) {
            float4 v = hp[k];
            hreg[4*k+0]=v.x; hreg[4*k+1]=v.y; hreg[4*k+2]=v.z; hreg[4*k+3]=v.w;
        }
    }

    if (y < 4) {
        uint4* xob = xproj_b + n * 16 + y * 4;
        #pragma unroll 1
        for (int ocl = 0; ocl < 2; ocl++) {
            const int oc = y * 2 + ocl;
            float4 p[4];
            #pragma unroll 1
            for (int b = 0; b < 4; b++)
                p[b] = dot32x4(w_s + b * 1024, hreg, oc);
            // pair-pack bf16: dword k = basis k pair {j0,j1}
            xob[ocl*2+0] = make_uint4(pkbf(p[0].x,p[0].y), pkbf(p[1].x,p[1].y),
                                      pkbf(p[2].x,p[2].y), pkbf(p[3].x,p[3].y));
            xob[ocl*2+1] = make_uint4(pkbf(p[0].z,p[0].w), pkbf(p[1].z,p[1].w),
                                      pkbf(p[2].z,p[2].w), pkbf(p[3].z,p[3].w));
        }
    } else {
        const int oc0 = (y - 4) * 4;
        #pragma unroll 1
        for (int m = 0; m < 3; m++) {
            const float* wbase = w_s + (m < 2 ? m * 1024 : 2048);
            float* outp = (m == 0 ? psrc : m == 1 ? pdst : selfp);
            float4 r[4];
            #pragma unroll 1
            for (int ocl = 0; ocl < 4; ocl++)
                r[ocl] = dot32x4(wbase, hreg, oc0 + ocl);
            float* o = outp + n * 32 + oc0 * 4;   // 64B line
            *(float4*)(o +  0) = r[0];
            *(float4*)(o +  4) = r[1];
            *(float4*)(o +  8) = r[2];
            *(float4*)(o + 12) = r[3];
        }
    }
}

// ==================== CSR edge kernel: 4 lanes/edge, 8 ch/lane =============
// R18: wave = 1 node, 16 edge-slots x 4 lanes. 10 vector-mem instructions
// cover 16 edges (0.625/edge vs R14's 0.875); avg degree 16 -> most waves
// run exactly ONE iteration (halves serial latency depth). Reduce = 2 DPP.
__global__ __launch_bounds__(256) void edge_csr_k(
    const int2* __restrict__ sorted2, const int* __restrict__ offs,
    const float* __restrict__ psrc, const float* __restrict__ pdst,
    const unsigned* __restrict__ t1b, const unsigned* __restrict__ t2b,
    const uint4* __restrict__ xproj_b, const float* __restrict__ selfp,
    const float* __restrict__ wcomp_l,
    const float* __restrict__ Bw, const float* __restrict__ Bb,
    float* __restrict__ h_next)
{
    // XCD-bijective swizzle: 25000 blocks, 25000 % 8 == 0.
    const int CPX = 25000 / 8;
    int bid = (int)blockIdx.x;
    bid = (bid % 8) * CPX + bid / 8;

    const int wib  = threadIdx.x >> 6;   // wave in block: 0..3
    const int lane = threadIdx.x & 63;
    const int grp  = lane >> 2;          // edge slot 0..15
    const int ci   = lane & 3;           // channel octet 0..3
    const int c8   = ci * 8;
    const int n    = bid * 4 + wib;      // dst node

    const int start = offs[n];
    const int end   = (n == NNODES - 1) ? NEDGES : offs[n + 1];
    const float4 bw0 = *(const float4*)(Bw + c8);
    const float4 bw1 = *(const float4*)(Bw + c8 + 4);
    const float bb = Bb[0];
    const float4 pd0 = *(const float4*)(pdst + n * 32 + c8);
    const float4 pd1 = *(const float4*)(pdst + n * 32 + c8 + 4);

    int e = start + grp;
    int2 rec = sorted2[(e < end) ? e : start];
    bool valid = (e < end);

    v2f acc0 = {0.f,0.f}, acc1 = {0.f,0.f}, acc2 = {0.f,0.f}, acc3 = {0.f,0.f};
    for (int e0 = start; e0 < end; e0 += 16) {
        int2 cur = rec;
        bool cv = valid;
        int en = e + 16;
        valid = (en < end);
        rec = sorted2[valid ? en : start];
        e = en;

        int s16 = cur.x;             // src*16 (uint4 index base)
        int et  = cur.y & 0xffff;
        int el  = cur.y >> 16;

        float4 ps0 = *(const float4*)(psrc + s16 * 2 + c8);
        float4 ps1 = *(const float4*)(psrc + s16 * 2 + c8 + 4);
        const uint4* xp = xproj_b + s16 + ci * 4;
        uint4 x0 = xp[0], x1 = xp[1], x2 = xp[2], x3 = xp[3];
        uint4 t1u = *(const uint4*)(t1b + et * 16 + ci * 4);
        uint4 t2u = *(const uint4*)(t2b + el * 16 + ci * 4);
        float4 c  = *(const float4*)(wcomp_l + et * 4);

        v2f ta0 = bf2f(t1u.x), ta1 = bf2f(t1u.y), ta2 = bf2f(t1u.z), ta3 = bf2f(t1u.w);
        v2f tb0 = bf2f(t2u.x), tb1 = bf2f(t2u.y), tb2 = bf2f(t2u.z), tb3 = bf2f(t2u.w);
        float z0 = fmaxf(ps0.x + pd0.x + ta0.x + tb0.x, 0.f);
        float z1 = fmaxf(ps0.y + pd0.y + ta0.y + tb0.y, 0.f);
        float z2 = fmaxf(ps0.z + pd0.z + ta1.x + tb1.x, 0.f);
        float z3 = fmaxf(ps0.w + pd0.w + ta1.y + tb1.y, 0.f);
        float z4 = fmaxf(ps1.x + pd1.x + ta2.x + tb2.x, 0.f);
        float z5 = fmaxf(ps1.y + pd1.y + ta2.y + tb2.y, 0.f);
        float z6 = fmaxf(ps1.z + pd1.z + ta3.x + tb3.x, 0.f);
        float z7 = fmaxf(ps1.w + pd1.w + ta3.y + tb3.y, 0.f);
        float d = fmaf(z0, bw0.x, fmaf(z1, bw0.y, fmaf(z2, bw0.z, z3 * bw0.w)));
        d = fmaf(z4, bw1.x, fmaf(z5, bw1.y, fmaf(z6, bw1.z, fmaf(z7, bw1.w, d))));
        d = dpp_add<DPP_XOR1>(d);
        d = dpp_add<DPP_XOR2>(d);
        float a = __builtin_amdgcn_rcpf(1.f + __expf(-(d + bb)));
        a = cv ? a : 0.f;

        v2f m;
        m = c.x*bf2f(x0.x) + c.y*bf2f(x0.y) + c.z*bf2f(x0.z) + c.w*bf2f(x0.w);
        acc0 += a * m;
        m = c.x*bf2f(x1.x) + c.y*bf2f(x1.y) + c.z*bf2f(x1.z) + c.w*bf2f(x1.w);
        acc1 += a * m;
        m = c.x*bf2f(x2.x) + c.y*bf2f(x2.y) + c.z*bf2f(x2.z) + c.w*bf2f(x2.w);
        acc2 += a * m;
        m = c.x*bf2f(x3.x) + c.y*bf2f(x3.y) + c.z*bf2f(x3.z) + c.w*bf2f(x3.w);
        acc3 += a * m;
    }
    // reduce across the 16 edge-slots (off the hot loop)
    #pragma unroll
    for (int s = 4; s <= 32; s <<= 1) {
        acc0.x += __shfl_xor(acc0.x, s);  acc0.y += __shfl_xor(acc0.y, s);
        acc1.x += __shfl_xor(acc1.x, s);  acc1.y += __shfl_xor(acc1.y, s);
        acc2.x += __shfl_xor(acc2.x, s);  acc2.y += __shfl_xor(acc2.y, s);
        acc3.x += __shfl_xor(acc3.x, s);  acc3.y += __shfl_xor(acc3.y, s);
    }
    if (lane < 4) {
        float4 sp0 = *(const float4*)(selfp + n * 32 + c8);
        float4 sp1 = *(const float4*)(selfp + n * 32 + c8 + 4);
        float4 hv0, hv1;
        hv0.x = fmaxf(acc0.x + sp0.x, 0.f);
        hv0.y = fmaxf(acc0.y + sp0.y, 0.f);
        hv0.z = fmaxf(acc1.x + sp0.z, 0.f);
        hv0.w = fmaxf(acc1.y + sp0.w, 0.f);
        hv1.x = fmaxf(acc2.x + sp1.x, 0.f);
        hv1.y = fmaxf(acc2.y + sp1.y, 0.f);
        hv1.z = fmaxf(acc3.x + sp1.z, 0.f);
        hv1.w = fmaxf(acc3.y + sp1.w, 0.f);
        *(float4*)(h_next + n * 32 + c8)     = hv0;
        *(float4*)(h_next + n * 32 + c8 + 4) = hv1;
    }
}

// ==================== per-graph mean (8 slices) + head/tail (y=8) ==========
__global__ __launch_bounds__(256) void mean_ht_k(
    const float* __restrict__ h, const int* __restrict__ head_ids,
    const int* __restrict__ tail_ids, float* __restrict__ g_acc,
    float* __restrict__ head_buf, float* __restrict__ tail_buf, int l)
{
    int g  = blockIdx.x;
    int sl = blockIdx.y;
    int i  = threadIdx.x & 31;
    if (sl == 8) {
        if (threadIdx.x < 32)
            head_buf[g*96 + l*32 + i] = h[head_ids[g]*32 + i];
        else if (threadIdx.x < 64)
            tail_buf[g*96 + l*32 + i] = h[tail_ids[g]*32 + i];
        return;
    }
    int sub = threadIdx.x >> 5;
    float acc = 0.f;
    for (int k = sub; k < 125; k += 8)
        acc += h[(g*NPER + sl*125 + k)*32 + i];
    __shared__ float red[8][32];
    red[sub][i] = acc;
    __syncthreads();
    if (threadIdx.x < 32) {
        float s2 = 0.f;
        #pragma unroll
        for (int k = 0; k < 8; k++) s2 += red[k][threadIdx.x];
        atomicAdd(&g_acc[g*96 + l*32 + threadIdx.x], s2 * (1.0f/NPER));
    }
}

// ==================== final readout ====================
__global__ __launch_bounds__(64) void readout_k(
    const float* __restrict__ g_acc, const float* __restrict__ head_buf,
    const float* __restrict__ tail_buf, const float* __restrict__ rel_tab,
    const int* __restrict__ rel_labels, const float* __restrict__ fc_w,
    const float* __restrict__ fc_b, float* __restrict__ out)
{
    int g = blockIdx.x;
    int t = threadIdx.x;
    float s = 0.f;
    for (int idx = t; idx < 320; idx += 64) {
        float v;
        if (idx < 96)       v = g_acc[g*96 + idx];
        else if (idx < 192) v = head_buf[g*96 + idx - 96];
        else if (idx < 288) v = tail_buf[g*96 + idx - 192];
        else                v = rel_tab[rel_labels[g]*32 + (idx - 288)];
        s += v * fc_w[idx];
    }
    s += __shfl_xor(s, 1, 64);
    s += __shfl_xor(s, 2, 64);
    s += __shfl_xor(s, 4, 64);
    s += __shfl_xor(s, 8, 64);
    s += __shfl_xor(s, 16, 64);
    s += __shfl_xor(s, 32, 64);
    if (t == 0) out[g] = s + fc_b[0];
}

extern "C" void kernel_launch(void* const* d_in, const int* in_sizes, int n_in,
                              void* d_out, int out_size, void* d_ws, size_t ws_size,
                              hipStream_t stream) {
    const float* feat        = (const float*)d_in[0];
    const float* basis       = (const float*)d_in[1];   // [3,4,32,32]
    const float* w_comp      = (const float*)d_in[2];   // [3,200,4]
    const float* self_loop_w = (const float*)d_in[3];   // [3,32,32]
    const float* A_w         = (const float*)d_in[4];   // [3,128,32]
    const float* A_b         = (const float*)d_in[5];   // [3,32]
    const float* B_w         = (const float*)d_in[6];   // [3,32,1]
    const float* B_b         = (const float*)d_in[7];   // [3,1]
    const float* attn_tab    = (const float*)d_in[8];   // [200,32]
    const float* rel_tab     = (const float*)d_in[9];   // [200,32]
    const float* fc_w        = (const float*)d_in[10];  // [320,1]
    const float* fc_b        = (const float*)d_in[11];  // [1]
    const int* src        = (const int*)d_in[12];
    const int* dst        = (const int*)d_in[13];
    const int* etype      = (const int*)d_in[14];
    const int* elabel     = (const int*)d_in[15];
    const int* head_ids   = (const int*)d_in[17];
    const int* tail_ids   = (const int*)d_in[18];
    const int* rel_labels = (const int*)d_in[19];

    float* ws = (float*)d_ws;
    size_t off = 0;
    float* h0    = ws + off; off += (size_t)NNODES * 32;
    float* h1    = ws + off; off += (size_t)NNODES * 32;
    uint4* xproj_b = (uint4*)(ws + off); off += (size_t)NNODES * 64;  // 256B/node
    float* psrc  = ws + off; off += (size_t)NNODES * 32;
    float* pdst  = ws + off; off += (size_t)NNODES * 32;
    float* selfp = ws + off; off += (size_t)NNODES * 32;
    unsigned* t1b = (unsigned*)(ws + off); off += 3200;
    unsigned* t2b = (unsigned*)(ws + off); off += 3200;
    float* g_acc    = ws + off; off += NGRAPH * 96;
    float* head_buf = ws + off; off += NGRAPH * 96;
    float* tail_buf = ws + off; off += NGRAPH * 96;
    int* count  = (int*)(ws + off); off += NNODES;
    int* offs   = (int*)(ws + off); off += NNODES;
    int* cursor = (int*)(ws + off); off += NNODES;
    off = (off + 3) & ~(size_t)3;               // 16 B align
    int2* sorted2 = (int2*)(ws + off); off += (size_t)NEDGES * 2;

    // ---- one-time per call: CSR by dst + zero mean accumulator ----
    zero2_k<<<(NNODES + 255)/256, 256, 0, stream>>>(count, g_acc);
    hist_k<<<(NEDGES + 255)/256, 256, 0, stream>>>(dst, count);
    scan_k<<<NGRAPH, 1024, 0, stream>>>(count, offs, cursor);
    scatter_k<<<(NEDGES + 255)/256, 256, 0, stream>>>(src, dst, etype, elabel,
                                                      cursor, sorted2);

    const float* hcur = feat;
    float* hbufs[2] = { h0, h1 };
    for (int l = 0; l < 3; l++) {
        dim3 ngrid((NNODES + 255)/256, 7);
        node_k<<<ngrid, 256, 0, stream>>>(
            hcur, basis + (size_t)l*4096, self_loop_w + (size_t)l*1024,
            A_w + (size_t)l*4096, A_b + (size_t)l*32, attn_tab,
            xproj_b, psrc, pdst, selfp, t1b, t2b);
        float* hn = hbufs[l & 1];
        edge_csr_k<<<NNODES/4, 256, 0, stream>>>(
            sorted2, offs, psrc, pdst, t1b, t2b, xproj_b, selfp,
            w_comp + (size_t)l*800, B_w + (size_t)l*32, B_b + l, hn);
        dim3 mgrid(NGRAPH, 9);
        mean_ht_k<<<mgrid, 256, 0, stream>>>(
            hn, head_ids, tail_ids, g_acc, head_buf, tail_buf, l);
        hcur = hn;
    }
    readout_k<<<NGRAPH, 64, 0, stream>>>(
        g_acc, head_buf, tail_buf, rel_tab, rel_labels, fc_w, fc_b, (float*)d_out);
}

// Round 19
// 491.310 us; speedup vs baseline: 1.2077x; 1.2077x over previous
//
#include <hip/hip_runtime.h>

#define NGRAPH 100
#define NPER   1000
#define NNODES 100000
#define NEDGES 1600000
#define EPG    16000   // edges per graph

typedef float v2f __attribute__((ext_vector_type(2)));

// DPP-based add of a permuted lane within a 16-lane row; VALU latency.
template <int CTRL>
__device__ __forceinline__ float dpp_add(float x) {
    int yi = __builtin_amdgcn_update_dpp(0, __float_as_int(x), CTRL, 0xF, 0xF, true);
    return x + __int_as_float(yi);
}
#define DPP_XOR1 0xB1   // quad_perm [1,0,3,2]
#define DPP_XOR2 0x4E   // quad_perm [2,3,0,1]
#define DPP_HMIR 0x141  // row_half_mirror: completes an 8-lane sum

// bf16x2 (packed in u32) -> 2 floats
__device__ __forceinline__ v2f bf2f(unsigned u) {
    v2f r;
    r.x = __uint_as_float(u << 16);
    r.y = __uint_as_float(u & 0xffff0000u);
    return r;
}
// 2 floats -> bf16x2 (round-to-nearest-ish)
__device__ __forceinline__ unsigned pkbf(float a, float b) {
    unsigned ua = (__float_as_uint(a) + 0x8000u) >> 16;
    unsigned ub = (__float_as_uint(b) + 0x8000u) & 0xffff0000u;
    return ua | ub;
}

// 4-channel dot for one node; weights stride STRIDE floats per d.
template <int STRIDE>
__device__ __forceinline__ float4 dot32x4s(const float* __restrict__ w,
                                           const float* hreg) {
    float4 a = {0.f, 0.f, 0.f, 0.f};
    #pragma unroll 4
    for (int d = 0; d < 32; d++) {
        float4 wv = *(const float4*)(w + d * STRIDE);
        a.x = fmaf(hreg[d], wv.x, a.x);
        a.y = fmaf(hreg[d], wv.y, a.y);
        a.z = fmaf(hreg[d], wv.z, a.z);
        a.w = fmaf(hreg[d], wv.w, a.w);
    }
    return a;
}

// ==================== utility: zero count + g_acc in one launch ============
__global__ __launch_bounds__(256) void zero2_k(int* __restrict__ count,
                                               float* __restrict__ g_acc) {
    int i = blockIdx.x * 256 + threadIdx.x;
    if (i < NNODES) count[i] = 0;
    if (i < NGRAPH * 96) g_acc[i] = 0.f;
}

// ==================== counting sort of edges by DST ====================
__global__ __launch_bounds__(256) void hist_k(const int* __restrict__ dst,
                                              int* __restrict__ count) {
    int e = blockIdx.x * 256 + threadIdx.x;
    if (e < NEDGES) atomicAdd(&count[dst[e]], 1);
}

__global__ __launch_bounds__(1024) void scan_k(const int* __restrict__ count,
                                               int* __restrict__ offs,
                                               int* __restrict__ cursor) {
    __shared__ int sc[1024];
    int t = threadIdx.x, g = blockIdx.x;
    int v = (t < NPER) ? count[g * NPER + t] : 0;
    sc[t] = v;
    __syncthreads();
    for (int s = 1; s < 1024; s <<= 1) {
        int add = (t >= s) ? sc[t - s] : 0;
        __syncthreads();
        sc[t] += add;
        __syncthreads();
    }
    if (t < NPER) {
        int start = g * EPG + sc[t] - v;   // exclusive
        offs[g * NPER + t]   = start;
        cursor[g * NPER + t] = start;
    }
}

// compressed record: {src*16, etype | elabel<<16}
__global__ __launch_bounds__(256) void scatter_k(
    const int* __restrict__ src, const int* __restrict__ dst,
    const int* __restrict__ et, const int* __restrict__ el,
    int* __restrict__ cursor, int2* __restrict__ sorted2) {
    int e = blockIdx.x * 256 + threadIdx.x;
    if (e >= NEDGES) return;
    int d = dst[e];
    int p = atomicAdd(&cursor[d], 1);
    sorted2[p] = make_int2(src[e] * 16, et[e] | (el[e] << 16));
}

// ==================== node projections: full-line writes, 1 node/thread ====
// grid (391, 5).
// y=0: xproj ch 0..15 (quads 0..3) -> 8 uint4 = full 128B line per thread
// y=1: xproj ch 16..31 (quads 4..7)
// y=2: psrc + pdst full 128B rows
// y=3: selfp full rows
// y=4: rel tables
// (R14 structure with xproj slices merged 4->2 to kill the 64B cross-block
//  partial-line writes behind WRITE_SIZE=148MB vs 96 ideal.)
__global__ __launch_bounds__(256, 4) void node_k(
    const float* __restrict__ h, const float* __restrict__ basis_l,
    const float* __restrict__ selfw_l, const float* __restrict__ Aw_l,
    const float* __restrict__ Ab_l, const float* __restrict__ attn_tab,
    uint4* __restrict__ xproj_b, float* __restrict__ psrc,
    float* __restrict__ pdst, float* __restrict__ selfp,
    unsigned* __restrict__ t1b, unsigned* __restrict__ t2b)
{
    const int y = blockIdx.y;
    if (y == 4) {   // rel tables: r = bid*4 + wave, 64 threads per r
        int r = blockIdx.x * 4 + (threadIdx.x >> 6);
        if (r >= 200) return;
        int t = threadIdx.x & 63;
        int o = t & 31;
        bool second = t >= 32;
        const float* at = attn_tab + r * 32;
        const float* W  = Aw_l + (second ? 96*32 : 64*32);
        float acc = second ? 0.f : Ab_l[o];
        #pragma unroll 8
        for (int d = 0; d < 32; d++) acc += at[d] * W[d*32 + o];
        float nb = __shfl_down(acc, 1);
        unsigned u = pkbf(acc, nb);
        if (!(o & 1)) (second ? t2b : t1b)[r*16 + (o >> 1)] = u;
        return;
    }

    __shared__ float w_s[2048];
    if (y < 2) {
        // basis channels [y*16, y*16+16): w_s[b*512 + d*16 + c]
        for (int k = threadIdx.x; k < 2048; k += 256) {
            int b = k >> 9, rem = k & 511, d = rem >> 4, c = rem & 15;
            w_s[k] = basis_l[b*1024 + d*32 + y*16 + c];
        }
    } else if (y == 2) {
        for (int k = threadIdx.x; k < 2048; k += 256) w_s[k] = Aw_l[k]; // A1|A2
    } else {
        for (int k = threadIdx.x; k < 1024; k += 256) w_s[k] = selfw_l[k];
    }
    __syncthreads();

    int n = blockIdx.x * 256 + threadIdx.x;
    if (n >= NNODES) return;

    float hreg[32];
    {
        const float4* hp = (const float4*)(h + n * 32);
        #pragma unroll
        for (int k = 0; k < 8; k++) {
            float4 v = hp[k];
            hreg[4*k+0]=v.x; hreg[4*k+1]=v.y; hreg[4*k+2]=v.z; hreg[4*k+3]=v.w;
        }
    }

    if (y < 2) {
        uint4* xob = xproj_b + n * 16 + y * 8;     // 128B line, one thread
        #pragma unroll 1
        for (int ocl = 0; ocl < 4; ocl++) {        // 4 channel-quads
            float4 p[4];
            #pragma unroll 1
            for (int b = 0; b < 4; b++)
                p[b] = dot32x4s<16>(w_s + b * 512 + ocl * 4, hreg);
            xob[ocl*2+0] = make_uint4(pkbf(p[0].x,p[0].y), pkbf(p[1].x,p[1].y),
                                      pkbf(p[2].x,p[2].y), pkbf(p[3].x,p[3].y));
            xob[ocl*2+1] = make_uint4(pkbf(p[0].z,p[0].w), pkbf(p[1].z,p[1].w),
                                      pkbf(p[2].z,p[2].w), pkbf(p[3].z,p[3].w));
        }
    } else if (y == 2) {
        #pragma unroll 1
        for (int m = 0; m < 2; m++) {
            float* outp = (m == 0 ? psrc : pdst);
            #pragma unroll 1
            for (int oc = 0; oc < 8; oc++) {
                float4 a = dot32x4s<32>(w_s + m * 1024 + oc * 4, hreg);
                *(float4*)(outp + n*32 + oc*4) = a;
            }
        }
    } else {
        #pragma unroll 1
        for (int oc = 0; oc < 8; oc++) {
            float4 a = dot32x4s<32>(w_s + oc * 4, hreg);
            *(float4*)(selfp + n*32 + oc*4) = a;
        }
    }
}

// ==================== CSR edge kernel: 8 lanes/edge, 4 ch/lane (R14) =======
// R14-verified local optimum: 7 gather instructions cover 8 edges; uniform
// bases + node-major rows; DPP 3-step reduce; next-record prefetch rotation.
__global__ __launch_bounds__(256) void edge_csr_k(
    const int2* __restrict__ sorted2, const int* __restrict__ offs,
    const float* __restrict__ psrc, const float* __restrict__ pdst,
    const unsigned* __restrict__ t1b, const unsigned* __restrict__ t2b,
    const uint4* __restrict__ xproj_b, const float* __restrict__ selfp,
    const float* __restrict__ wcomp_l,
    const float* __restrict__ Bw, const float* __restrict__ Bb,
    float* __restrict__ h_next)
{
    // XCD-bijective swizzle: 25000 blocks, 25000 % 8 == 0.
    const int CPX = 25000 / 8;
    int bid = (int)blockIdx.x;
    bid = (bid % 8) * CPX + bid / 8;

    const int wib  = threadIdx.x >> 6;   // wave in block: 0..3
    const int lane = threadIdx.x & 63;
    const int grp  = lane >> 3;          // edge slot 0..7
    const int ci   = lane & 7;           // channel quad 0..7
    const int c4   = ci * 4;
    const int n    = bid * 4 + wib;      // dst node

    const int start = offs[n];
    const int end   = (n == NNODES - 1) ? NEDGES : offs[n + 1];
    const float4 bw = *(const float4*)(Bw + c4);
    const float bb = Bb[0];
    const float4 pd = *(const float4*)(pdst + n * 32 + c4);

    int e = start + grp;
    int2 rec = sorted2[(e < end) ? e : start];
    bool valid = (e < end);

    v2f acc01 = {0.f, 0.f}, acc23 = {0.f, 0.f};
    for (int e0 = start; e0 < end; e0 += 8) {
        int2 cur = rec;
        bool cv = valid;
        int en = e + 8;
        valid = (en < end);
        rec = sorted2[valid ? en : start];
        e = en;

        int s16 = cur.x;             // src*16 (uint4 index base)
        int et  = cur.y & 0xffff;
        int el  = cur.y >> 16;

        float4 ps  = *(const float4*)(psrc + s16 * 2 + c4);
        uint4  xlo = xproj_b[s16 + ci * 2];
        uint4  xhi = xproj_b[s16 + ci * 2 + 1];
        uint2  t1u = *(const uint2*)(t1b + et * 16 + ci * 2);
        uint2  t2u = *(const uint2*)(t2b + el * 16 + ci * 2);
        float4 c   = *(const float4*)(wcomp_l + et * 4);

        v2f t1a = bf2f(t1u.x), t1c = bf2f(t1u.y);
        v2f t2a = bf2f(t2u.x), t2c = bf2f(t2u.y);
        float z0 = fmaxf(ps.x + pd.x + t1a.x + t2a.x, 0.f);
        float z1 = fmaxf(ps.y + pd.y + t1a.y + t2a.y, 0.f);
        float z2 = fmaxf(ps.z + pd.z + t1c.x + t2c.x, 0.f);
        float z3 = fmaxf(ps.w + pd.w + t1c.y + t2c.y, 0.f);
        float d = fmaf(z0, bw.x, fmaf(z1, bw.y, fmaf(z2, bw.z, z3 * bw.w)));
        d = dpp_add<DPP_XOR1>(d);
        d = dpp_add<DPP_XOR2>(d);
        d = dpp_add<DPP_HMIR>(d);
        float a = __builtin_amdgcn_rcpf(1.f + __expf(-(d + bb)));
        a = cv ? a : 0.f;

        v2f b0 = bf2f(xlo.x), b1 = bf2f(xlo.y), b2 = bf2f(xlo.z), b3 = bf2f(xlo.w);
        v2f m01 = c.x * b0 + c.y * b1 + c.z * b2 + c.w * b3;
        v2f g0 = bf2f(xhi.x), g1 = bf2f(xhi.y), g2 = bf2f(xhi.z), g3 = bf2f(xhi.w);
        v2f m23 = c.x * g0 + c.y * g1 + c.z * g2 + c.w * g3;
        acc01 += a * m01;
        acc23 += a * m23;
    }
    // reduce across the 8 edge-slots (off the hot loop)
    #pragma unroll
    for (int s = 8; s <= 32; s <<= 1) {
        acc01.x += __shfl_xor(acc01.x, s);
        acc01.y += __shfl_xor(acc01.y, s);
        acc23.x += __shfl_xor(acc23.x, s);
        acc23.y += __shfl_xor(acc23.y, s);
    }
    if (lane < 8) {
        float4 sp = *(const float4*)(selfp + n * 32 + c4);
        float4 hv;
        hv.x = fmaxf(acc01.x + sp.x, 0.f);
        hv.y = fmaxf(acc01.y + sp.y, 0.f);
        hv.z = fmaxf(acc23.x + sp.z, 0.f);
        hv.w = fmaxf(acc23.y + sp.w, 0.f);
        *(float4*)(h_next + n * 32 + c4) = hv;
    }
}

// ==================== per-graph mean (8 slices) + head/tail (y=8) ==========
__global__ __launch_bounds__(256) void mean_ht_k(
    const float* __restrict__ h, const int* __restrict__ head_ids,
    const int* __restrict__ tail_ids, float* __restrict__ g_acc,
    float* __restrict__ head_buf, float* __restrict__ tail_buf, int l)
{
    int g  = blockIdx.x;
    int sl = blockIdx.y;
    int i  = threadIdx.x & 31;
    if (sl == 8) {
        if (threadIdx.x < 32)
            head_buf[g*96 + l*32 + i] = h[head_ids[g]*32 + i];
        else if (threadIdx.x < 64)
            tail_buf[g*96 + l*32 + i] = h[tail_ids[g]*32 + i];
        return;
    }
    int sub = threadIdx.x >> 5;
    float acc = 0.f;
    for (int k = sub; k < 125; k += 8)
        acc += h[(g*NPER + sl*125 + k)*32 + i];
    __shared__ float red[8][32];
    red[sub][i] = acc;
    __syncthreads();
    if (threadIdx.x < 32) {
        float s2 = 0.f;
        #pragma unroll
        for (int k = 0; k < 8; k++) s2 += red[k][threadIdx.x];
        atomicAdd(&g_acc[g*96 + l*32 + threadIdx.x], s2 * (1.0f/NPER));
    }
}

// ==================== final readout ====================
__global__ __launch_bounds__(64) void readout_k(
    const float* __restrict__ g_acc, const float* __restrict__ head_buf,
    const float* __restrict__ tail_buf, const float* __restrict__ rel_tab,
    const int* __restrict__ rel_labels, const float* __restrict__ fc_w,
    const float* __restrict__ fc_b, float* __restrict__ out)
{
    int g = blockIdx.x;
    int t = threadIdx.x;
    float s = 0.f;
    for (int idx = t; idx < 320; idx += 64) {
        float v;
        if (idx < 96)       v = g_acc[g*96 + idx];
        else if (idx < 192) v = head_buf[g*96 + idx - 96];
        else if (idx < 288) v = tail_buf[g*96 + idx - 192];
        else                v = rel_tab[rel_labels[g]*32 + (idx - 288)];
        s += v * fc_w[idx];
    }
    s += __shfl_xor(s, 1, 64);
    s += __shfl_xor(s, 2, 64);
    s += __shfl_xor(s, 4, 64);
    s += __shfl_xor(s, 8, 64);
    s += __shfl_xor(s, 16, 64);
    s += __shfl_xor(s, 32, 64);
    if (t == 0) out[g] = s + fc_b[0];
}

extern "C" void kernel_launch(void* const* d_in, const int* in_sizes, int n_in,
                              void* d_out, int out_size, void* d_ws, size_t ws_size,
                              hipStream_t stream) {
    const float* feat        = (const float*)d_in[0];
    const float* basis       = (const float*)d_in[1];   // [3,4,32,32]
    const float* w_comp      = (const float*)d_in[2];   // [3,200,4]
    const float* self_loop_w = (const float*)d_in[3];   // [3,32,32]
    const float* A_w         = (const float*)d_in[4];   // [3,128,32]
    const float* A_b         = (const float*)d_in[5];   // [3,32]
    const float* B_w         = (const float*)d_in[6];   // [3,32,1]
    const float* B_b         = (const float*)d_in[7];   // [3,1]
    const float* attn_tab    = (const float*)d_in[8];   // [200,32]
    const float* rel_tab     = (const float*)d_in[9];   // [200,32]
    const float* fc_w        = (const float*)d_in[10];  // [320,1]
    const float* fc_b        = (const float*)d_in[11];  // [1]
    const int* src        = (const int*)d_in[12];
    const int* dst        = (const int*)d_in[13];
    const int* etype      = (const int*)d_in[14];
    const int* elabel     = (const int*)d_in[15];
    const int* head_ids   = (const int*)d_in[17];
    const int* tail_ids   = (const int*)d_in[18];
    const int* rel_labels = (const int*)d_in[19];

    float* ws = (float*)d_ws;
    size_t off = 0;
    float* h0    = ws + off; off += (size_t)NNODES * 32;
    float* h1    = ws + off; off += (size_t)NNODES * 32;
    uint4* xproj_b = (uint4*)(ws + off); off += (size_t)NNODES * 64;  // 256B/node
    float* psrc  = ws + off; off += (size_t)NNODES * 32;
    float* pdst  = ws + off; off += (size_t)NNODES * 32;
    float* selfp = ws + off; off += (size_t)NNODES * 32;
    unsigned* t1b = (unsigned*)(ws + off); off += 3200;
    unsigned* t2b = (unsigned*)(ws + off); off += 3200;
    float* g_acc    = ws + off; off += NGRAPH * 96;
    float* head_buf = ws + off; off += NGRAPH * 96;
    float* tail_buf = ws + off; off += NGRAPH * 96;
    int* count  = (int*)(ws + off); off += NNODES;
    int* offs   = (int*)(ws + off); off += NNODES;
    int* cursor = (int*)(ws + off); off += NNODES;
    off = (off + 3) & ~(size_t)3;               // 16 B align
    int2* sorted2 = (int2*)(ws + off); off += (size_t)NEDGES * 2;

    // ---- one-time per call: CSR by dst + zero mean accumulator ----
    zero2_k<<<(NNODES + 255)/256, 256, 0, stream>>>(count, g_acc);
    hist_k<<<(NEDGES + 255)/256, 256, 0, stream>>>(dst, count);
    scan_k<<<NGRAPH, 1024, 0, stream>>>(count, offs, cursor);
    scatter_k<<<(NEDGES + 255)/256, 256, 0, stream>>>(src, dst, etype, elabel,
                                                      cursor, sorted2);

    const float* hcur = feat;
    float* hbufs[2] = { h0, h1 };
    for (int l = 0; l < 3; l++) {
        dim3 ngrid((NNODES + 255)/256, 5);
        node_k<<<ngrid, 256, 0, stream>>>(
            hcur, basis + (size_t)l*4096, self_loop_w + (size_t)l*1024,
            A_w + (size_t)l*4096, A_b + (size_t)l*32, attn_tab,
            xproj_b, psrc, pdst, selfp, t1b, t2b);
        float* hn = hbufs[l & 1];
        edge_csr_k<<<NNODES/4, 256, 0, stream>>>(
            sorted2, offs, psrc, pdst, t1b, t2b, xproj_b, selfp,
            w_comp + (size_t)l*800, B_w + (size_t)l*32, B_b + l, hn);
        dim3 mgrid(NGRAPH, 9);
        mean_ht_k<<<mgrid, 256, 0, stream>>>(
            hn, head_ids, tail_ids, g_acc, head_buf, tail_buf, l);
        hcur = hn;
    }
    readout_k<<<NGRAPH, 64, 0, stream>>>(
        g_acc, head_buf, tail_buf, rel_tab, rel_labels, fc_w, fc_b, (float*)d_out);
}

// Round 21
// 381.420 us; speedup vs baseline: 1.5556x; 1.2881x over previous
//
#include <hip/hip_runtime.h>

#define NGRAPH 100
#define NPER   1000
#define NNODES 100000
#define NEDGES 1600000
#define EPG    16000   // edges per graph

typedef float v2f  __attribute__((ext_vector_type(2)));
typedef float f32x4 __attribute__((ext_vector_type(4)));
typedef short short8 __attribute__((ext_vector_type(8)));

// DPP-based ops; VALU latency.
template <int CTRL>
__device__ __forceinline__ float dpp_add(float x) {
    int yi = __builtin_amdgcn_update_dpp(0, __float_as_int(x), CTRL, 0xF, 0xF, true);
    return x + __int_as_float(yi);
}
template <int CTRL>
__device__ __forceinline__ float dpp_mov(float x) {
    int yi = __builtin_amdgcn_update_dpp(0, __float_as_int(x), CTRL, 0xF, 0xF, true);
    return __int_as_float(yi);
}
#define DPP_XOR1 0xB1   // quad_perm [1,0,3,2]
#define DPP_XOR2 0x4E   // quad_perm [2,3,0,1]
#define DPP_HMIR 0x141  // row_half_mirror

// bf16x2 (packed in u32) -> 2 floats
__device__ __forceinline__ v2f bf2f(unsigned u) {
    v2f r;
    r.x = __uint_as_float(u << 16);
    r.y = __uint_as_float(u & 0xffff0000u);
    return r;
}
// 2 floats -> bf16x2
__device__ __forceinline__ unsigned pkbf(float a, float b) {
    unsigned ua = (__float_as_uint(a) + 0x8000u) >> 16;
    unsigned ub = (__float_as_uint(b) + 0x8000u) & 0xffff0000u;
    return ua | ub;
}
__device__ __forceinline__ short bfs(float x) {
    return (short)((__float_as_uint(x) + 0x8000u) >> 16);
}
__device__ __forceinline__ float bf2f1(short s) {
    return __uint_as_float(((unsigned)(unsigned short)s) << 16);
}

// ==================== utility: zero count + g_acc ====================
__global__ __launch_bounds__(256) void zero2_k(int* __restrict__ count,
                                               float* __restrict__ g_acc) {
    int i = blockIdx.x * 256 + threadIdx.x;
    if (i < NNODES) count[i] = 0;
    if (i < NGRAPH * 96) g_acc[i] = 0.f;
}

// ==================== counting sort of edges by DST ====================
__global__ __launch_bounds__(256) void hist_k(const int* __restrict__ dst,
                                              int* __restrict__ count) {
    int e = blockIdx.x * 256 + threadIdx.x;
    if (e < NEDGES) atomicAdd(&count[dst[e]], 1);
}

__global__ __launch_bounds__(1024) void scan_k(const int* __restrict__ count,
                                               int* __restrict__ offs,
                                               int* __restrict__ cursor) {
    __shared__ int sc[1024];
    int t = threadIdx.x, g = blockIdx.x;
    int v = (t < NPER) ? count[g * NPER + t] : 0;
    sc[t] = v;
    __syncthreads();
    for (int s = 1; s < 1024; s <<= 1) {
        int add = (t >= s) ? sc[t - s] : 0;
        __syncthreads();
        sc[t] += add;
        __syncthreads();
    }
    if (t < NPER) {
        int start = g * EPG + sc[t] - v;   // exclusive
        offs[g * NPER + t]   = start;
        cursor[g * NPER + t] = start;
    }
}

// compressed record: {src*16, etype | elabel<<16}
__global__ __launch_bounds__(256) void scatter_k(
    const int* __restrict__ src, const int* __restrict__ dst,
    const int* __restrict__ et, const int* __restrict__ el,
    int* __restrict__ cursor, int2* __restrict__ sorted2) {
    int e = blockIdx.x * 256 + threadIdx.x;
    if (e >= NEDGES) return;
    int d = dst[e];
    int p = atomicAdd(&cursor[d], 1);
    sorted2[p] = make_int2(src[e] * 16, et[e] | (el[e] << 16));
}

// ==================== B-fragment precompute (all layers) ====================
// Wcat[k][n], n=0..223: [basis b0..b3 | A1 | A2 | self], each 32 cols.
// B frag (mfma_f32_16x16x32_bf16): lane l holds col n=16t+(l&15),
// k = (l>>4)*8 + s; dword packs k pairs (2s, 2s+1) low/high.
__global__ __launch_bounds__(64) void wfrag_k(
    const float* __restrict__ basis, const float* __restrict__ selfw,
    const float* __restrict__ A_w, uint4* __restrict__ bfrag)
{
    int t = blockIdx.x;          // tile 0..13
    int l = blockIdx.y;          // layer
    int ln = threadIdx.x;
    int j = ln & 15, grp = ln >> 4;
    int n = t * 16 + j;
    int mat = n >> 5, o = n & 31;
    const float* W;
    if (mat < 4)       W = basis + l * 4096 + mat * 1024;
    else if (mat == 4) W = A_w + l * 4096;            // A1: rows 0..31
    else if (mat == 5) W = A_w + l * 4096 + 1024;     // A2: rows 32..63
    else               W = selfw + l * 1024;
    unsigned w0 = pkbf(W[(grp*8+0)*32 + o], W[(grp*8+1)*32 + o]);
    unsigned w1 = pkbf(W[(grp*8+2)*32 + o], W[(grp*8+3)*32 + o]);
    unsigned w2 = pkbf(W[(grp*8+4)*32 + o], W[(grp*8+5)*32 + o]);
    unsigned w3 = pkbf(W[(grp*8+6)*32 + o], W[(grp*8+7)*32 + o]);
    bfrag[(l * 14 + t) * 64 + ln] = make_uint4(w0, w1, w2, w3);
}

// ==================== rel tables (all layers) ====================
__global__ __launch_bounds__(256) void rel3_k(
    const float* __restrict__ attn_tab, const float* __restrict__ A_w,
    const float* __restrict__ A_b, unsigned* __restrict__ t1b,
    unsigned* __restrict__ t2b)
{
    int l = blockIdx.y;
    int r = blockIdx.x * 4 + (threadIdx.x >> 6);
    if (r >= 200) return;
    int t = threadIdx.x & 63;
    int o = t & 31;
    bool second = t >= 32;
    const float* at = attn_tab + r * 32;
    const float* W  = A_w + l * 4096 + (second ? 96*32 : 64*32);
    float acc = second ? 0.f : A_b[l*32 + o];
    #pragma unroll 8
    for (int d = 0; d < 32; d++) acc += at[d] * W[d*32 + o];
    float nb = __shfl_down(acc, 1);
    unsigned u = pkbf(acc, nb);
    if (!(o & 1)) (second ? t2b : t1b)[l*3200 + r*16 + (o >> 1)] = u;
}

// ==================== MFMA node projections ====================
// Wave: 16 nodes x 224 outputs. A split hi/lo for f32-grade accuracy on h.
// D layout (m89): col n = lane&15, node row = (lane>>4)*4 + reg.
__global__ __launch_bounds__(256, 4) void node_mfma_k(
    const float* __restrict__ h, const uint4* __restrict__ bfrag_l,
    uint4* __restrict__ xproj_b, float* __restrict__ psrc,
    float* __restrict__ pdst, float* __restrict__ selfp)
{
    const int wave = threadIdx.x >> 6;
    const int lane = threadIdx.x & 63;
    const int base = blockIdx.x * 64 + wave * 16;
    const int j    = lane & 15;
    const int grp  = lane >> 4;
    const int par  = j & 1;

    // ---- A fragment: node row base+j, k = grp*8 .. +7 (hi/lo split) ----
    int m = base + j;
    int mc = (m < NNODES) ? m : NNODES - 1;
    const float4* hp = (const float4*)(h + mc * 32 + grp * 8);
    float4 h0 = hp[0], h1 = hp[1];
    float hf[8] = {h0.x, h0.y, h0.z, h0.w, h1.x, h1.y, h1.z, h1.w};
    short8 ahi, alo;
    #pragma unroll
    for (int s = 0; s < 8; s++) {
        short hi = bfs(hf[s]);
        ahi[s] = hi;
        alo[s] = bfs(hf[s] - bf2f1(hi));
    }

    const f32x4 zero = {0.f, 0.f, 0.f, 0.f};

    // ---- f32 output tiles 8..13: psrc | pdst | selfp ----
    #pragma unroll 1
    for (int t = 8; t < 14; t++) {
        uint4 braw = bfrag_l[t * 64 + lane];
        short8 b = *(short8*)&braw;
        f32x4 d = __builtin_amdgcn_mfma_f32_16x16x32_bf16(ahi, b, zero, 0, 0, 0);
        d = __builtin_amdgcn_mfma_f32_16x16x32_bf16(alo, b, d, 0, 0, 0);
        float* outp = (t < 10) ? psrc : (t < 12) ? pdst : selfp;
        int ch = (t & 1) * 16 + j;
        #pragma unroll
        for (int q = 0; q < 4; q++) {
            int mq = base + grp * 4 + q;
            if (mq < NNODES) outp[mq * 32 + ch] = d[q];
        }
    }

    // ---- basis tiles 0..7 -> xproj (bf16 pair-packed, b-minor) ----
    f32x4 db[8];
    #pragma unroll 1
    for (int t = 0; t < 8; t++) {
        uint4 braw = bfrag_l[t * 64 + lane];
        short8 b = *(short8*)&braw;
        f32x4 d = __builtin_amdgcn_mfma_f32_16x16x32_bf16(ahi, b, zero, 0, 0, 0);
        db[t] = __builtin_amdgcn_mfma_f32_16x16x32_bf16(alo, b, d, 0, 0, 0);
    }
    // R20 bugfix: exchange BOTH channel-halves via DPP, THEN select by
    // parity (previous version selected before exchanging -> mixed halves).
    #pragma unroll
    for (int q = 0; q < 4; q++) {
        int mq = base + grp * 4 + q;
        unsigned pk[4];
        #pragma unroll
        for (int b2 = 0; b2 < 4; b2++) {
            float v0 = db[2*b2][q];       // own ch = j        (half 0)
            float v1 = db[2*b2 + 1][q];   // own ch = 16 + j   (half 1)
            float o0 = dpp_mov<DPP_XOR1>(v0);  // neighbor's half-0 value
            float o1 = dpp_mov<DPP_XOR1>(v1);  // neighbor's half-1 value
            // even lane (par=0): pair (j>>1) of half0 = {ch j, ch j+1}
            // odd  lane (par=1): pair 8+(j>>1) of half1 = {ch 16+j-1, 16+j}
            pk[b2] = par ? pkbf(o1, v1) : pkbf(v0, o0);
        }
        if (mq < NNODES)
            xproj_b[mq * 16 + par * 8 + (j >> 1)] =
                make_uint4(pk[0], pk[1], pk[2], pk[3]);
    }
}

// ==================== CSR edge kernel: 8 lanes/edge, 4 ch/lane (R14) =======
__global__ __launch_bounds__(256) void edge_csr_k(
    const int2* __restrict__ sorted2, const int* __restrict__ offs,
    const float* __restrict__ psrc, const float* __restrict__ pdst,
    const unsigned* __restrict__ t1b, const unsigned* __restrict__ t2b,
    const uint4* __restrict__ xproj_b, const float* __restrict__ selfp,
    const float* __restrict__ wcomp_l,
    const float* __restrict__ Bw, const float* __restrict__ Bb,
    float* __restrict__ h_next)
{
    // XCD-bijective swizzle: 25000 blocks, 25000 % 8 == 0.
    const int CPX = 25000 / 8;
    int bid = (int)blockIdx.x;
    bid = (bid % 8) * CPX + bid / 8;

    const int wib  = threadIdx.x >> 6;
    const int lane = threadIdx.x & 63;
    const int grp  = lane >> 3;          // edge slot 0..7
    const int ci   = lane & 7;           // channel quad 0..7
    const int c4   = ci * 4;
    const int n    = bid * 4 + wib;

    const int start = offs[n];
    const int end   = (n == NNODES - 1) ? NEDGES : offs[n + 1];
    const float4 bw = *(const float4*)(Bw + c4);
    const float bb = Bb[0];
    const float4 pd = *(const float4*)(pdst + n * 32 + c4);

    int e = start + grp;
    int2 rec = sorted2[(e < end) ? e : start];
    bool valid = (e < end);

    v2f acc01 = {0.f, 0.f}, acc23 = {0.f, 0.f};
    for (int e0 = start; e0 < end; e0 += 8) {
        int2 cur = rec;
        bool cv = valid;
        int en = e + 8;
        valid = (en < end);
        rec = sorted2[valid ? en : start];
        e = en;

        int s16 = cur.x;
        int et  = cur.y & 0xffff;
        int el  = cur.y >> 16;

        float4 ps  = *(const float4*)(psrc + s16 * 2 + c4);
        uint4  xlo = xproj_b[s16 + ci * 2];
        uint4  xhi = xproj_b[s16 + ci * 2 + 1];
        uint2  t1u = *(const uint2*)(t1b + et * 16 + ci * 2);
        uint2  t2u = *(const uint2*)(t2b + el * 16 + ci * 2);
        float4 c   = *(const float4*)(wcomp_l + et * 4);

        v2f t1a = bf2f(t1u.x), t1c = bf2f(t1u.y);
        v2f t2a = bf2f(t2u.x), t2c = bf2f(t2u.y);
        float z0 = fmaxf(ps.x + pd.x + t1a.x + t2a.x, 0.f);
        float z1 = fmaxf(ps.y + pd.y + t1a.y + t2a.y, 0.f);
        float z2 = fmaxf(ps.z + pd.z + t1c.x + t2c.x, 0.f);
        float z3 = fmaxf(ps.w + pd.w + t1c.y + t2c.y, 0.f);
        float d = fmaf(z0, bw.x, fmaf(z1, bw.y, fmaf(z2, bw.z, z3 * bw.w)));
        d = dpp_add<DPP_XOR1>(d);
        d = dpp_add<DPP_XOR2>(d);
        d = dpp_add<DPP_HMIR>(d);
        float a = __builtin_amdgcn_rcpf(1.f + __expf(-(d + bb)));
        a = cv ? a : 0.f;

        v2f b0 = bf2f(xlo.x), b1 = bf2f(xlo.y), b2 = bf2f(xlo.z), b3 = bf2f(xlo.w);
        v2f m01 = c.x * b0 + c.y * b1 + c.z * b2 + c.w * b3;
        v2f g0 = bf2f(xhi.x), g1 = bf2f(xhi.y), g2 = bf2f(xhi.z), g3 = bf2f(xhi.w);
        v2f m23 = c.x * g0 + c.y * g1 + c.z * g2 + c.w * g3;
        acc01 += a * m01;
        acc23 += a * m23;
    }
    #pragma unroll
    for (int s = 8; s <= 32; s <<= 1) {
        acc01.x += __shfl_xor(acc01.x, s);
        acc01.y += __shfl_xor(acc01.y, s);
        acc23.x += __shfl_xor(acc23.x, s);
        acc23.y += __shfl_xor(acc23.y, s);
    }
    if (lane < 8) {
        float4 sp = *(const float4*)(selfp + n * 32 + c4);
        float4 hv;
        hv.x = fmaxf(acc01.x + sp.x, 0.f);
        hv.y = fmaxf(acc01.y + sp.y, 0.f);
        hv.z = fmaxf(acc23.x + sp.z, 0.f);
        hv.w = fmaxf(acc23.y + sp.w, 0.f);
        *(float4*)(h_next + n * 32 + c4) = hv;
    }
}

// ==================== per-graph mean (8 slices) + head/tail (y=8) ==========
__global__ __launch_bounds__(256) void mean_ht_k(
    const float* __restrict__ h, const int* __restrict__ head_ids,
    const int* __restrict__ tail_ids, float* __restrict__ g_acc,
    float* __restrict__ head_buf, float* __restrict__ tail_buf, int l)
{
    int g  = blockIdx.x;
    int sl = blockIdx.y;
    int i  = threadIdx.x & 31;
    if (sl == 8) {
        if (threadIdx.x < 32)
            head_buf[g*96 + l*32 + i] = h[head_ids[g]*32 + i];
        else if (threadIdx.x < 64)
            tail_buf[g*96 + l*32 + i] = h[tail_ids[g]*32 + i];
        return;
    }
    int sub = threadIdx.x >> 5;
    float acc = 0.f;
    for (int k = sub; k < 125; k += 8)
        acc += h[(g*NPER + sl*125 + k)*32 + i];
    __shared__ float red[8][32];
    red[sub][i] = acc;
    __syncthreads();
    if (threadIdx.x < 32) {
        float s2 = 0.f;
        #pragma unroll
        for (int k = 0; k < 8; k++) s2 += red[k][threadIdx.x];
        atomicAdd(&g_acc[g*96 + l*32 + threadIdx.x], s2 * (1.0f/NPER));
    }
}

// ==================== final readout ====================
__global__ __launch_bounds__(64) void readout_k(
    const float* __restrict__ g_acc, const float* __restrict__ head_buf,
    const float* __restrict__ tail_buf, const float* __restrict__ rel_tab,
    const int* __restrict__ rel_labels, const float* __restrict__ fc_w,
    const float* __restrict__ fc_b, float* __restrict__ out)
{
    int g = blockIdx.x;
    int t = threadIdx.x;
    float s = 0.f;
    for (int idx = t; idx < 320; idx += 64) {
        float v;
        if (idx < 96)       v = g_acc[g*96 + idx];
        else if (idx < 192) v = head_buf[g*96 + idx - 96];
        else if (idx < 288) v = tail_buf[g*96 + idx - 192];
        else                v = rel_tab[rel_labels[g]*32 + (idx - 288)];
        s += v * fc_w[idx];
    }
    s += __shfl_xor(s, 1, 64);
    s += __shfl_xor(s, 2, 64);
    s += __shfl_xor(s, 4, 64);
    s += __shfl_xor(s, 8, 64);
    s += __shfl_xor(s, 16, 64);
    s += __shfl_xor(s, 32, 64);
    if (t == 0) out[g] = s + fc_b[0];
}

extern "C" void kernel_launch(void* const* d_in, const int* in_sizes, int n_in,
                              void* d_out, int out_size, void* d_ws, size_t ws_size,
                              hipStream_t stream) {
    const float* feat        = (const float*)d_in[0];
    const float* basis       = (const float*)d_in[1];   // [3,4,32,32]
    const float* w_comp      = (const float*)d_in[2];   // [3,200,4]
    const float* self_loop_w = (const float*)d_in[3];   // [3,32,32]
    const float* A_w         = (const float*)d_in[4];   // [3,128,32]
    const float* A_b         = (const float*)d_in[5];   // [3,32]
    const float* B_w         = (const float*)d_in[6];   // [3,32,1]
    const float* B_b         = (const float*)d_in[7];   // [3,1]
    const float* attn_tab    = (const float*)d_in[8];   // [200,32]
    const float* rel_tab     = (const float*)d_in[9];   // [200,32]
    const float* fc_w        = (const float*)d_in[10];  // [320,1]
    const float* fc_b        = (const float*)d_in[11];  // [1]
    const int* src        = (const int*)d_in[12];
    const int* dst        = (const int*)d_in[13];
    const int* etype      = (const int*)d_in[14];
    const int* elabel     = (const int*)d_in[15];
    const int* head_ids   = (const int*)d_in[17];
    const int* tail_ids   = (const int*)d_in[18];
    const int* rel_labels = (const int*)d_in[19];

    float* ws = (float*)d_ws;
    size_t off = 0;
    float* h0    = ws + off; off += (size_t)NNODES * 32;
    float* h1    = ws + off; off += (size_t)NNODES * 32;
    uint4* xproj_b = (uint4*)(ws + off); off += (size_t)NNODES * 64;  // 256B/node
    float* psrc  = ws + off; off += (size_t)NNODES * 32;
    float* pdst  = ws + off; off += (size_t)NNODES * 32;
    float* selfp = ws + off; off += (size_t)NNODES * 32;
    unsigned* t1b = (unsigned*)(ws + off); off += 3 * 3200;
    unsigned* t2b = (unsigned*)(ws + off); off += 3 * 3200;
    uint4* bfrag  = (uint4*)(ws + off);   off += 3 * 14 * 64 * 4;
    float* g_acc    = ws + off; off += NGRAPH * 96;
    float* head_buf = ws + off; off += NGRAPH * 96;
    float* tail_buf = ws + off; off += NGRAPH * 96;
    int* count  = (int*)(ws + off); off += NNODES;
    int* offs   = (int*)(ws + off); off += NNODES;
    int* cursor = (int*)(ws + off); off += NNODES;
    off = (off + 3) & ~(size_t)3;               // 16 B align
    int2* sorted2 = (int2*)(ws + off); off += (size_t)NEDGES * 2;

    // ---- one-time per call: CSR by dst + weight frags + rel tables ----
    zero2_k<<<(NNODES + 255)/256, 256, 0, stream>>>(count, g_acc);
    hist_k<<<(NEDGES + 255)/256, 256, 0, stream>>>(dst, count);
    scan_k<<<NGRAPH, 1024, 0, stream>>>(count, offs, cursor);
    scatter_k<<<(NEDGES + 255)/256, 256, 0, stream>>>(src, dst, etype, elabel,
                                                      cursor, sorted2);
    dim3 wgrid(14, 3);
    wfrag_k<<<wgrid, 64, 0, stream>>>(basis, self_loop_w, A_w, bfrag);
    dim3 rgrid(50, 3);
    rel3_k<<<rgrid, 256, 0, stream>>>(attn_tab, A_w, A_b, t1b, t2b);

    const float* hcur = feat;
    float* hbufs[2] = { h0, h1 };
    for (int l = 0; l < 3; l++) {
        node_mfma_k<<<(NNODES + 63)/64, 256, 0, stream>>>(
            hcur, bfrag + (size_t)l*14*64, xproj_b, psrc, pdst, selfp);
        float* hn = hbufs[l & 1];
        edge_csr_k<<<NNODES/4, 256, 0, stream>>>(
            sorted2, offs, psrc, pdst, t1b + l*3200, t2b + l*3200,
            xproj_b, selfp, w_comp + (size_t)l*800,
            B_w + (size_t)l*32, B_b + l, hn);
        dim3 mgrid(NGRAPH, 9);
        mean_ht_k<<<mgrid, 256, 0, stream>>>(
            hn, head_ids, tail_ids, g_acc, head_buf, tail_buf, l);
        hcur = hn;
    }
    readout_k<<<NGRAPH, 64, 0, stream>>>(
        g_acc, head_buf, tail_buf, rel_tab, rel_labels, fc_w, fc_b, (float*)d_out);
}